// Round 22
// baseline (189.646 us; speedup 1.0000x reference)
//
#include <hip/hip_runtime.h>

#define S_LEN 4096
#define DMODEL 1024
#define NH 16
#define NKV 4
#define HDIM 64
#define NQKV 1536  /* (16+2*4)*64 */

typedef __attribute__((ext_vector_type(8))) short bfrag8;
typedef __attribute__((ext_vector_type(4))) float f32x4_t;

__device__ __forceinline__ unsigned short f2bf(float f) {
  unsigned int u = __builtin_bit_cast(unsigned int, f);
  return (unsigned short)((u + 0x7fffu + ((u >> 16) & 1u)) >> 16);
}

// packed f32x2 -> bf16x2, single HW instruction
__device__ __forceinline__ unsigned int cvtpk_bf16(float lo, float hi) {
  unsigned int r;
  asm("v_cvt_pk_bf16_f32 %0, %1, %2" : "=v"(r) : "v"(lo), "v"(hi));
  return r;
}

// bare v_exp_f32 (libm exp2f adds ~6-inst fixup; our domain [-1e30, +8] is safe)
__device__ __forceinline__ float fexp2(float x) {
  float r;
  asm("v_exp_f32 %0, %1" : "=v"(r) : "v"(x));
  return r;
}

__device__ __forceinline__ float fmax3(float a, float b, float c) {
  float r;
  asm("v_max3_f32 %0, %1, %2, %3" : "=v"(r) : "v"(a), "v"(b), "v"(c));
  return r;
}

typedef __attribute__((address_space(3))) unsigned char lds_uc;
typedef const __attribute__((address_space(1))) unsigned char glob_uc;
__device__ __forceinline__ void gl16(const void* g, void* l) {
  __builtin_amdgcn_global_load_lds((glob_uc*)g, (lds_uc*)l, 16, 0, 0);
}

// ---------------- fused preprocessing: x->bf16 | wqkv^T | wo^T (grid-sectioned) ----------------
__global__ void preprocess(const float* __restrict__ x, const float* __restrict__ wqkv,
                           const float* __restrict__ wo,
                           unsigned short* __restrict__ xb, unsigned short* __restrict__ wqkvT,
                           unsigned short* __restrict__ woT) {
  __shared__ float tile[32][33];
  int b = blockIdx.x;
  int t = threadIdx.x;
  if (b < 4096) {  // convert x (4096x1024 f32 -> bf16), 4 elts/thread
    int idx = (b * 256 + t) * 4;
    float4 v = *reinterpret_cast<const float4*>(x + idx);
    xb[idx + 0] = f2bf(v.x);
    xb[idx + 1] = f2bf(v.y);
    xb[idx + 2] = f2bf(v.z);
    xb[idx + 3] = f2bf(v.w);
    return;
  }
  int tx = t & 31, ty = t >> 5;  // 32 x 8
  const float* in;
  unsigned short* out;
  int ldin, ldout, c0, r0;
  if (b < 4096 + 1536) {  // wqkv (1024x1536) -> wqkvT (1536x1024)
    int id = b - 4096;
    c0 = (id % 48) * 32;
    r0 = (id / 48) * 32;
    in = wqkv; out = wqkvT; ldin = NQKV; ldout = DMODEL;
  } else {                // wo (1024x1024) -> woT
    int id = b - 4096 - 1536;
    c0 = (id & 31) * 32;
    r0 = (id >> 5) * 32;
    in = wo; out = woT; ldin = DMODEL; ldout = DMODEL;
  }
  for (int i = 0; i < 4; ++i) {
    int r = r0 + ty + i * 8;
    tile[ty + i * 8][tx] = in[(size_t)r * ldin + c0 + tx];
  }
  __syncthreads();
  for (int i = 0; i < 4; ++i) {
    int c = c0 + ty + i * 8;
    out[(size_t)c * ldout + r0 + tx] = f2bf(tile[tx][ty + i * 8]);
  }
}

// ---------------- fused RoPE (Q pre-scaled into exp2 domain) + V transpose ----------------
__global__ void rope_vt(const float* __restrict__ qkv,
                        const float* __restrict__ pcos, const float* __restrict__ psin,
                        unsigned short* __restrict__ Qh, unsigned short* __restrict__ Kh,
                        unsigned short* __restrict__ Vt) {
  int b = blockIdx.x;
  int t = threadIdx.x;
  if (b < 4096) {  // rope on row s=b
    const float SCL = 0.125f * 1.44269504f;
    int s = b;
    const float* row = qkv + (size_t)s * NQKV;
    for (int p = t; p < 640; p += 256) {
      int i = p & 31;
      float c = pcos[s * 32 + i], sn = psin[s * 32 + i];
      if (p < 512) {
        int h = p >> 5;
        float te = row[h * 64 + 2 * i], to = row[h * 64 + 2 * i + 1];
        size_t base = ((size_t)h * S_LEN + s) * 64;
        Qh[base + 2 * i]     = f2bf((te * c - to * sn) * SCL);
        Qh[base + 2 * i + 1] = f2bf((te * sn + to * c) * SCL);
      } else {
        int hk = (p - 512) >> 5;
        float te = row[1024 + hk * 64 + 2 * i], to = row[1024 + hk * 64 + 2 * i + 1];
        size_t base = ((size_t)hk * S_LEN + s) * 64;
        Kh[base + 2 * i]     = f2bf(te * c - to * sn);
        Kh[base + 2 * i + 1] = f2bf(te * sn + to * c);
      }
    }
    return;
  }
  // V transpose: [s][d] (cols 1280+hk*64+d of qkv) -> Vt[hk][d][s]
  __shared__ float tile[32][33];
  int id = b - 4096;              // 0..1023
  int dt = id & 1;                // d-tile
  int st = (id >> 1) & 127;       // s-tile
  int hk = id >> 8;               // kv head
  int tx = t & 31, ty = t >> 5;
  const float* inb = qkv + 1280 + hk * 64 + dt * 32;
  unsigned short* outb = Vt + (size_t)hk * HDIM * S_LEN + (size_t)dt * 32 * S_LEN;
  int s0 = st * 32;
  for (int i = 0; i < 4; ++i) {
    int r = s0 + ty + i * 8;
    tile[ty + i * 8][tx] = inb[(size_t)r * NQKV + tx];
  }
  __syncthreads();
  for (int i = 0; i < 4; ++i) {
    int d = ty + i * 8;
    outb[(size_t)d * S_LEN + s0 + tx] = f2bf(tile[tx][d]);
  }
}

// ---------------- bf16 MFMA GEMM, 64x128 tile, BK=64: C = A * Bt^T ----------------
__global__ __launch_bounds__(256) void gemm_bf16(
    const unsigned short* __restrict__ A,
    const unsigned short* __restrict__ Bt,
    float* __restrict__ C, int M, int N, int K) {
  __shared__ __align__(16) unsigned short As[64 * 64];    // 8 KB
  __shared__ __align__(16) unsigned short Bs[128 * 64];   // 16 KB
  int m0 = blockIdx.x * 64, n0 = blockIdx.y * 128;
  int t = threadIdx.x, lane = t & 63, wid = t >> 6;
  int wm = (wid >> 1) * 32, wn = (wid & 1) * 64;
  int fr = lane & 15, kb = lane >> 4;
  int srow = t >> 3, scol = (t & 7) * 8;
  const unsigned short* Ag0 = A + (size_t)(m0 + srow) * K + scol;
  const unsigned short* Ag1 = A + (size_t)(m0 + 32 + srow) * K + scol;
  const unsigned short* Bg0 = Bt + (size_t)(n0 + srow) * K + scol;
  const unsigned short* Bg1 = Bt + (size_t)(n0 + 32 + srow) * K + scol;
  const unsigned short* Bg2 = Bt + (size_t)(n0 + 64 + srow) * K + scol;
  const unsigned short* Bg3 = Bt + (size_t)(n0 + 96 + srow) * K + scol;
  char* AsD0 = (char*)As + wid * 1024;
  char* AsD1 = (char*)As + 4096 + wid * 1024;
  char* BsD0 = (char*)Bs + wid * 1024;
  char* BsD1 = (char*)Bs + 4096 + wid * 1024;
  char* BsD2 = (char*)Bs + 8192 + wid * 1024;
  char* BsD3 = (char*)Bs + 12288 + wid * 1024;

  f32x4_t acc[2][4];
#pragma unroll
  for (int r = 0; r < 2; ++r)
#pragma unroll
    for (int c = 0; c < 4; ++c) acc[r][c] = (f32x4_t){0.f, 0.f, 0.f, 0.f};

  for (int k0 = 0; k0 < K; k0 += 64) {
    __syncthreads();
    gl16(Ag0 + k0, AsD0);
    gl16(Ag1 + k0, AsD1);
    gl16(Bg0 + k0, BsD0);
    gl16(Bg1 + k0, BsD1);
    gl16(Bg2 + k0, BsD2);
    gl16(Bg3 + k0, BsD3);
    __syncthreads();
    bfrag8 af[2][2], bfr[4][2];
#pragma unroll
    for (int rb = 0; rb < 2; ++rb)
#pragma unroll
      for (int h = 0; h < 2; ++h)
        af[rb][h] = *reinterpret_cast<const bfrag8*>(&As[(wm + rb * 16 + fr) * 64 + h * 32 + kb * 8]);
#pragma unroll
    for (int cb = 0; cb < 4; ++cb)
#pragma unroll
      for (int h = 0; h < 2; ++h)
        bfr[cb][h] = *reinterpret_cast<const bfrag8*>(&Bs[(wn + cb * 16 + fr) * 64 + h * 32 + kb * 8]);
#pragma unroll
    for (int rb = 0; rb < 2; ++rb)
#pragma unroll
      for (int cb = 0; cb < 4; ++cb) {
        acc[rb][cb] = __builtin_amdgcn_mfma_f32_16x16x32_bf16(af[rb][0], bfr[cb][0], acc[rb][cb], 0, 0, 0);
        acc[rb][cb] = __builtin_amdgcn_mfma_f32_16x16x32_bf16(af[rb][1], bfr[cb][1], acc[rb][cb], 0, 0, 0);
      }
  }
  int rowg = (lane >> 4) * 4, colg = lane & 15;
#pragma unroll
  for (int rb = 0; rb < 2; ++rb)
#pragma unroll
    for (int cb = 0; cb < 4; ++cb)
#pragma unroll
      for (int j = 0; j < 4; ++j) {
        int r = m0 + wm + rb * 16 + rowg + j;
        int c = n0 + wn + cb * 16 + colg;
        C[(size_t)r * N + c] = acc[rb][cb][j];
      }
}

// ---------------- flash attention (R13/R16-proven body + R19 XCD map): causal, GQA ----------------
// Qh [NH][S][64] (pre-scaled), Kh [NKV][S][64], Vt [NKV][64][S], aout [S][NH*64] bf16
// Block: 256 thr = 4 waves; all share one (head, 32-row q-tile), each takes 1/4 of KV range.
// Grid: 2048 blocks, longest-first. XCD-locality: hk = bid & 3 -> one kv-group per XCD (L2-resident).
// MERGE NOTE (R7 bug): m_r lives on lane fr (q-row g*16+fr); acc[g][dt][j] holds q-row g*16+rloc+j.
// Any factor derived from m MUST be broadcast via __shfl(x, rloc+j) before touching acc.
// l_r is LANE-PARTIAL (this lane's 16 columns); cross-kb reduced ONCE in the epilogue (R13).
__global__ __launch_bounds__(256) void flash_attn(
    const unsigned short* __restrict__ Qh,
    const unsigned short* __restrict__ Kh,
    const unsigned short* __restrict__ Vt,
    unsigned short* __restrict__ aout) {
  __shared__ __align__(16) char SMEM[18432];  // union: Pl[4][4KB] | 2 x merge region [36][64] f32
  int bid = blockIdx.x;
  int hk = bid & 3;                             // XCD-locality: one kv-group per XCD
  int head = hk * 4 + ((bid >> 2) & 3);
  int qt = 127 - (bid >> 4);                    // longest chains dispatch first
  int qrow0 = qt * 32;
  int t = threadIdx.x, lane = t & 63, wid = t >> 6;
  int fr = lane & 15, kb = lane >> 4, rloc = kb * 4;
  char* Pw = SMEM + wid * 4096;
  int swz = (fr & 7) << 4;  // XOR swizzle within 128B P rows

  const unsigned short* Qbase = Qh + ((size_t)head * S_LEN + qrow0) * 64;
  bfrag8 qf[2][2];
  qf[0][0] = *reinterpret_cast<const bfrag8*>(Qbase + fr * 64 + kb * 8);
  qf[0][1] = *reinterpret_cast<const bfrag8*>(Qbase + fr * 64 + 32 + kb * 8);
  qf[1][0] = *reinterpret_cast<const bfrag8*>(Qbase + (16 + fr) * 64 + kb * 8);
  qf[1][1] = *reinterpret_cast<const bfrag8*>(Qbase + (16 + fr) * 64 + 32 + kb * 8);

  const unsigned short* Kt = Kh + (size_t)hk * S_LEN * 64;
  const unsigned short* Vb = Vt + (size_t)hk * 64 * S_LEN;
  int koff = fr * 64 + kb * 8;
  int voff = fr * S_LEN + kb * 8;

  float m_r[2] = {-1e30f, -1e30f}, l_r[2] = {0.f, 0.f};
  f32x4_t acc[2][4];
#pragma unroll
  for (int g = 0; g < 2; ++g)
#pragma unroll
    for (int dt = 0; dt < 4; ++dt) acc[g][dt] = (f32x4_t){0.f, 0.f, 0.f, 0.f};

  int ntt = (qrow0 + 95) / 64;
  int nf = (qrow0 >= 63) ? ((qrow0 - 63) / 64 + 1) : 0;
  int c0 = (wid * ntt) >> 2, c1 = ((wid + 1) * ntt) >> 2;

  if (c0 < c1) {
    bfrag8 kf[4][2];
    {
      const unsigned short* K0 = Kt + c0 * 64 * 64 + koff;
#pragma unroll
      for (int ct = 0; ct < 4; ++ct) {
        kf[ct][0] = *reinterpret_cast<const bfrag8*>(K0 + ct * 1024);
        kf[ct][1] = *reinterpret_cast<const bfrag8*>(K0 + ct * 1024 + 32);
      }
    }
    for (int kt = c0; kt < c1; ++kt) {
      int kv0 = kt * 64;
      const unsigned short* Vtile = Vb + kv0 + voff;
      bfrag8 vf[2][4];
#pragma unroll
      for (int hh = 0; hh < 2; ++hh)
#pragma unroll
        for (int dt = 0; dt < 4; ++dt)
          vf[hh][dt] = *reinterpret_cast<const bfrag8*>(Vtile + dt * 16 * S_LEN + hh * 32);
      __builtin_amdgcn_sched_barrier(0);
      // swapped QK^T
      f32x4_t sc[2][4];
      __builtin_amdgcn_s_setprio(1);
#pragma unroll
      for (int ct = 0; ct < 4; ++ct) {
        f32x4_t z0 = (f32x4_t){0.f, 0.f, 0.f, 0.f};
        z0 = __builtin_amdgcn_mfma_f32_16x16x32_bf16(kf[ct][0], qf[0][0], z0, 0, 0, 0);
        sc[0][ct] = __builtin_amdgcn_mfma_f32_16x16x32_bf16(kf[ct][1], qf[0][1], z0, 0, 0, 0);
        f32x4_t z1 = (f32x4_t){0.f, 0.f, 0.f, 0.f};
        z1 = __builtin_amdgcn_mfma_f32_16x16x32_bf16(kf[ct][0], qf[1][0], z1, 0, 0, 0);
        sc[1][ct] = __builtin_amdgcn_mfma_f32_16x16x32_bf16(kf[ct][1], qf[1][1], z1, 0, 0, 0);
      }
      __builtin_amdgcn_s_setprio(0);
      // prefetch next tile's K
      if (kt + 1 < c1) {
        const unsigned short* Kn = Kt + (kv0 + 64) * 64 + koff;
#pragma unroll
        for (int ct = 0; ct < 4; ++ct) {
          kf[ct][0] = *reinterpret_cast<const bfrag8*>(Kn + ct * 1024);
          kf[ct][1] = *reinterpret_cast<const bfrag8*>(Kn + ct * 1024 + 32);
        }
      }
      __builtin_amdgcn_sched_barrier(0);
      if (kt >= nf) {
#pragma unroll
        for (int g = 0; g < 2; ++g) {
          int grow = qrow0 + g * 16 + fr;
#pragma unroll
          for (int ct = 0; ct < 4; ++ct)
#pragma unroll
            for (int j = 0; j < 4; ++j)
              sc[g][ct][j] = ((kv0 + ct * 16 + kb * 4 + j) <= grow) ? sc[g][ct][j] : -1e30f;
        }
      }
      // row max: v_max3 chains + 2 shuffles (m must be row-consistent before exp)
      float pmax[2];
#pragma unroll
      for (int g = 0; g < 2; ++g) {
        float pm = fmax3(sc[g][0][0], sc[g][0][1], sc[g][0][2]);
        pm = fmax3(pm, sc[g][0][3], sc[g][1][0]);
        pm = fmax3(pm, sc[g][1][1], sc[g][1][2]);
        pm = fmax3(pm, sc[g][1][3], sc[g][2][0]);
        pm = fmax3(pm, sc[g][2][1], sc[g][2][2]);
        pm = fmax3(pm, sc[g][2][3], sc[g][3][0]);
        pm = fmax3(pm, sc[g][3][1], sc[g][3][2]);
        pm = fmaxf(pm, sc[g][3][3]);
        pm = fmaxf(pm, __shfl_xor(pm, 16));
        pmax[g] = fmaxf(pm, __shfl_xor(pm, 32));
      }
      // defer-max (rescale factor a is row-uniform -> applies to lane-partial l too)
      bool need = (pmax[0] > m_r[0] + 8.0f) || (pmax[1] > m_r[1] + 8.0f);
      if (__any(need)) {
#pragma unroll
        for (int g = 0; g < 2; ++g) {
          float mnew = fmaxf(m_r[g], pmax[g]);
          float a = fexp2(m_r[g] - mnew);
          l_r[g] *= a;
          m_r[g] = mnew;
#pragma unroll
          for (int j = 0; j < 4; ++j) {
            float aj = __shfl(a, rloc + j);
#pragma unroll
            for (int dt = 0; dt < 4; ++dt) acc[g][dt][j] *= aj;
          }
        }
      }
      // P = exp2(s - m); TREE sum into LANE-PARTIAL l (no per-tile shuffles) [R13]
#pragma unroll
      for (int g = 0; g < 2; ++g) {
        float st[4];
#pragma unroll
        for (int ct = 0; ct < 4; ++ct) {
          float p0 = fexp2(sc[g][ct][0] - m_r[g]);
          float p1 = fexp2(sc[g][ct][1] - m_r[g]);
          float p2 = fexp2(sc[g][ct][2] - m_r[g]);
          float p3 = fexp2(sc[g][ct][3] - m_r[g]);
          sc[g][ct][0] = p0; sc[g][ct][1] = p1; sc[g][ct][2] = p2; sc[g][ct][3] = p3;
          st[ct] = (p0 + p1) + (p2 + p3);
        }
        l_r[g] += (st[0] + st[1]) + (st[2] + st[3]);
      }
      // P -> per-wave LDS
#pragma unroll
      for (int g = 0; g < 2; ++g)
#pragma unroll
        for (int ct = 0; ct < 4; ++ct) {
          unsigned int u01 = cvtpk_bf16(sc[g][ct][0], sc[g][ct][1]);
          unsigned int u23 = cvtpk_bf16(sc[g][ct][2], sc[g][ct][3]);
          unsigned long long w = ((unsigned long long)u23 << 32) | u01;
          *reinterpret_cast<unsigned long long*>(
              Pw + (g * 16 + fr) * 128 + ((ct * 32 + kb * 8) ^ swz)) = w;
        }
      // PV
      __builtin_amdgcn_s_setprio(1);
#pragma unroll
      for (int hh = 0; hh < 2; ++hh) {
        bfrag8 pa0 = *reinterpret_cast<const bfrag8*>(Pw + fr * 128 + ((hh * 64 + kb * 16) ^ swz));
        bfrag8 pa1 = *reinterpret_cast<const bfrag8*>(Pw + (16 + fr) * 128 + ((hh * 64 + kb * 16) ^ swz));
#pragma unroll
        for (int dt = 0; dt < 4; ++dt) {
          acc[0][dt] = __builtin_amdgcn_mfma_f32_16x16x32_bf16(pa0, vf[hh][dt], acc[0][dt], 0, 0, 0);
          acc[1][dt] = __builtin_amdgcn_mfma_f32_16x16x32_bf16(pa1, vf[hh][dt], acc[1][dt], 0, 0, 0);
        }
      }
      __builtin_amdgcn_s_setprio(0);
    }
  }

  // ---- log-tree merge: (0<-1, 2<-3) then (0<-2). Regions reuse P LDS. ----
  // l stays lane-partial through the merge (same layout in all waves; ca/cb row-uniform per lane).
  float* stgA = (float*)SMEM;
  float* stgB = (float*)(SMEM + 9216);
  __syncthreads();
  if (wid == 1 || wid == 3) {
    float* R = (wid == 1) ? stgA : stgB;
#pragma unroll
    for (int g = 0; g < 2; ++g) {
#pragma unroll
      for (int dt = 0; dt < 4; ++dt)
#pragma unroll
        for (int j = 0; j < 4; ++j)
          R[(g * 16 + dt * 4 + j) * 64 + lane] = acc[g][dt][j];
      R[(32 + g * 2) * 64 + lane] = m_r[g];
      R[(33 + g * 2) * 64 + lane] = l_r[g];
    }
  }
  __syncthreads();
  if (wid == 0 || wid == 2) {
    float* R = (wid == 0) ? stgA : stgB;
#pragma unroll
    for (int g = 0; g < 2; ++g) {
      float mo = R[(32 + g * 2) * 64 + lane], lo = R[(33 + g * 2) * 64 + lane];
      float mm = fmaxf(m_r[g], mo);
      float ca = fexp2(m_r[g] - mm), cb = fexp2(mo - mm);
      l_r[g] = l_r[g] * ca + lo * cb;
      m_r[g] = mm;
#pragma unroll
      for (int j = 0; j < 4; ++j) {
        float caj = __shfl(ca, rloc + j);   // row-matched factors (R7 fix)
        float cbj = __shfl(cb, rloc + j);
#pragma unroll
        for (int dt = 0; dt < 4; ++dt)
          acc[g][dt][j] = acc[g][dt][j] * caj + R[(g * 16 + dt * 4 + j) * 64 + lane] * cbj;
      }
    }
    if (wid == 2) {
#pragma unroll
      for (int g = 0; g < 2; ++g) {
#pragma unroll
        for (int dt = 0; dt < 4; ++dt)
#pragma unroll
          for (int j = 0; j < 4; ++j)
            stgB[(g * 16 + dt * 4 + j) * 64 + lane] = acc[g][dt][j];
        stgB[(32 + g * 2) * 64 + lane] = m_r[g];
        stgB[(33 + g * 2) * 64 + lane] = l_r[g];
      }
    }
  }
  __syncthreads();
  if (wid == 0) {
#pragma unroll
    for (int g = 0; g < 2; ++g) {
      float mo = stgB[(32 + g * 2) * 64 + lane], lo = stgB[(33 + g * 2) * 64 + lane];
      float mm = fmaxf(m_r[g], mo);
      float ca = fexp2(m_r[g] - mm), cb = fexp2(mo - mm);
      l_r[g] = l_r[g] * ca + lo * cb;
#pragma unroll
      for (int j = 0; j < 4; ++j) {
        float caj = __shfl(ca, rloc + j);   // row-matched factors (R7 fix)
        float cbj = __shfl(cb, rloc + j);
#pragma unroll
        for (int dt = 0; dt < 4; ++dt)
          acc[g][dt][j] = acc[g][dt][j] * caj + stgB[(g * 16 + dt * 4 + j) * 64 + lane] * cbj;
      }
    }
    // reduce lane-partial l across kb groups ONCE, then normalize and write
#pragma unroll
    for (int g = 0; g < 2; ++g) {
      l_r[g] += __shfl_xor(l_r[g], 16);
      l_r[g] += __shfl_xor(l_r[g], 32);
    }
#pragma unroll
    for (int g = 0; g < 2; ++g)
#pragma unroll
      for (int j = 0; j < 4; ++j) {
        float lj = __shfl(l_r[g], rloc + j);
        float inv = 1.0f / lj;
        int grow = qrow0 + g * 16 + rloc + j;
#pragma unroll
        for (int dt = 0; dt < 4; ++dt)
          aout[(size_t)grow * (NH * HDIM) + head * 64 + dt * 16 + fr] = f2bf(acc[g][dt][j] * inv);
      }
  }
}

// ---------------- launch ----------------
extern "C" void kernel_launch(void* const* d_in, const int* in_sizes, int n_in,
                              void* d_out, int out_size, void* d_ws, size_t ws_size,
                              hipStream_t stream) {
  const float* x    = (const float*)d_in[0];
  const float* pcos = (const float*)d_in[1];
  const float* psin = (const float*)d_in[2];
  const float* wqkv = (const float*)d_in[3];
  const float* wo   = (const float*)d_in[4];
  float* out = (float*)d_out;

  char* ws = (char*)d_ws;
  unsigned short* xb    = (unsigned short*)ws;  ws += (size_t)S_LEN * DMODEL * 2;
  unsigned short* wqkvT = (unsigned short*)ws;  ws += (size_t)NQKV * DMODEL * 2;
  unsigned short* woT   = (unsigned short*)ws;  ws += (size_t)DMODEL * DMODEL * 2;
  float*          qkv   = (float*)ws;           ws += (size_t)S_LEN * NQKV * 4;
  unsigned short* Qh    = (unsigned short*)ws;  ws += (size_t)NH * S_LEN * HDIM * 2;
  unsigned short* Kh    = (unsigned short*)ws;  ws += (size_t)NKV * S_LEN * HDIM * 2;
  unsigned short* Vt    = (unsigned short*)ws;  ws += (size_t)NKV * HDIM * S_LEN * 2;
  unsigned short* aoutb = (unsigned short*)ws;  ws += (size_t)S_LEN * NH * HDIM * 2;

  preprocess<<<dim3(4096 + 1536 + 1024), 256, 0, stream>>>(x, wqkv, wo, xb, wqkvT, woT);
  gemm_bf16<<<dim3(S_LEN / 64, NQKV / 128), 256, 0, stream>>>(xb, wqkvT, qkv, S_LEN, NQKV, DMODEL);
  rope_vt<<<dim3(4096 + 1024), 256, 0, stream>>>(qkv, pcos, psin, Qh, Kh, Vt);
  flash_attn<<<dim3(2048), 256, 0, stream>>>(Qh, Kh, Vt, aoutb);
  gemm_bf16<<<dim3(S_LEN / 64, DMODEL / 128), 256, 0, stream>>>(aoutb, woT, out, S_LEN, DMODEL, DMODEL);
}

// Round 23
// 182.018 us; speedup vs baseline: 1.0419x; 1.0419x over previous
//
#include <hip/hip_runtime.h>

#define S_LEN 4096
#define DMODEL 1024
#define NH 16
#define NKV 4
#define HDIM 64
#define NQKV 1536  /* (16+2*4)*64 */

typedef __attribute__((ext_vector_type(8))) short bfrag8;
typedef __attribute__((ext_vector_type(4))) float f32x4_t;

__device__ __forceinline__ unsigned short f2bf(float f) {
  unsigned int u = __builtin_bit_cast(unsigned int, f);
  return (unsigned short)((u + 0x7fffu + ((u >> 16) & 1u)) >> 16);
}

// packed f32x2 -> bf16x2, single HW instruction
__device__ __forceinline__ unsigned int cvtpk_bf16(float lo, float hi) {
  unsigned int r;
  asm("v_cvt_pk_bf16_f32 %0, %1, %2" : "=v"(r) : "v"(lo), "v"(hi));
  return r;
}

// bare v_exp_f32 (libm exp2f adds ~6-inst fixup; our domain [-1e30, +8] is safe)
__device__ __forceinline__ float fexp2(float x) {
  float r;
  asm("v_exp_f32 %0, %1" : "=v"(r) : "v"(x));
  return r;
}

__device__ __forceinline__ float fmax3(float a, float b, float c) {
  float r;
  asm("v_max3_f32 %0, %1, %2, %3" : "=v"(r) : "v"(a), "v"(b), "v"(c));
  return r;
}

typedef __attribute__((address_space(3))) unsigned char lds_uc;
typedef const __attribute__((address_space(1))) unsigned char glob_uc;
__device__ __forceinline__ void gl16(const void* g, void* l) {
  __builtin_amdgcn_global_load_lds((glob_uc*)g, (lds_uc*)l, 16, 0, 0);
}

// ---------------- fused preprocessing: x->bf16 | wqkv^T | wo^T (grid-sectioned) ----------------
__global__ void preprocess(const float* __restrict__ x, const float* __restrict__ wqkv,
                           const float* __restrict__ wo,
                           unsigned short* __restrict__ xb, unsigned short* __restrict__ wqkvT,
                           unsigned short* __restrict__ woT) {
  __shared__ float tile[32][33];
  int b = blockIdx.x;
  int t = threadIdx.x;
  if (b < 4096) {  // convert x (4096x1024 f32 -> bf16), 4 elts/thread
    int idx = (b * 256 + t) * 4;
    float4 v = *reinterpret_cast<const float4*>(x + idx);
    xb[idx + 0] = f2bf(v.x);
    xb[idx + 1] = f2bf(v.y);
    xb[idx + 2] = f2bf(v.z);
    xb[idx + 3] = f2bf(v.w);
    return;
  }
  int tx = t & 31, ty = t >> 5;  // 32 x 8
  const float* in;
  unsigned short* out;
  int ldin, ldout, c0, r0;
  if (b < 4096 + 1536) {  // wqkv (1024x1536) -> wqkvT (1536x1024)
    int id = b - 4096;
    c0 = (id % 48) * 32;
    r0 = (id / 48) * 32;
    in = wqkv; out = wqkvT; ldin = NQKV; ldout = DMODEL;
  } else {                // wo (1024x1024) -> woT
    int id = b - 4096 - 1536;
    c0 = (id & 31) * 32;
    r0 = (id >> 5) * 32;
    in = wo; out = woT; ldin = DMODEL; ldout = DMODEL;
  }
  for (int i = 0; i < 4; ++i) {
    int r = r0 + ty + i * 8;
    tile[ty + i * 8][tx] = in[(size_t)r * ldin + c0 + tx];
  }
  __syncthreads();
  for (int i = 0; i < 4; ++i) {
    int c = c0 + ty + i * 8;
    out[(size_t)c * ldout + r0 + tx] = f2bf(tile[tx][ty + i * 8]);
  }
}

// ---------------- GEMM1 fused: qkv = xb @ wqkvT^T with RoPE + scatter epilogue ----------------
// 64x128 tile, BK=64, same body as gemm_bf16. Each wave's 64-col span = exactly ONE head
// ((n0+wn) is 64-aligned), so the Q/K/V epilogue branch is wave-uniform.
// RoPE pair (d, d^1) lives in lane^1 (colg=lane&15, same row): one shfl_xor gives the partner.
// Math path identical to old qkv(f32)->rope_vt: same f32 acc in, same f2bf out.
__global__ __launch_bounds__(256) void gemm_qkv_rope(
    const unsigned short* __restrict__ A,    // xb [4096][1024]
    const unsigned short* __restrict__ Bt,   // wqkvT [1536][1024]
    const float* __restrict__ pcos, const float* __restrict__ psin,
    unsigned short* __restrict__ Qh,         // [NH][S][64] (pre-scaled)
    unsigned short* __restrict__ Kh,         // [NKV][S][64]
    unsigned short* __restrict__ Vt) {       // [NKV][64][S]
  const int K = DMODEL;
  __shared__ __align__(16) unsigned short As[64 * 64];    // 8 KB
  __shared__ __align__(16) unsigned short Bs[128 * 64];   // 16 KB
  int m0 = blockIdx.x * 64, n0 = blockIdx.y * 128;
  int t = threadIdx.x, lane = t & 63, wid = t >> 6;
  int wm = (wid >> 1) * 32, wn = (wid & 1) * 64;
  int fr = lane & 15, kb = lane >> 4;
  int srow = t >> 3, scol = (t & 7) * 8;
  const unsigned short* Ag0 = A + (size_t)(m0 + srow) * K + scol;
  const unsigned short* Ag1 = A + (size_t)(m0 + 32 + srow) * K + scol;
  const unsigned short* Bg0 = Bt + (size_t)(n0 + srow) * K + scol;
  const unsigned short* Bg1 = Bt + (size_t)(n0 + 32 + srow) * K + scol;
  const unsigned short* Bg2 = Bt + (size_t)(n0 + 64 + srow) * K + scol;
  const unsigned short* Bg3 = Bt + (size_t)(n0 + 96 + srow) * K + scol;
  char* AsD0 = (char*)As + wid * 1024;
  char* AsD1 = (char*)As + 4096 + wid * 1024;
  char* BsD0 = (char*)Bs + wid * 1024;
  char* BsD1 = (char*)Bs + 4096 + wid * 1024;
  char* BsD2 = (char*)Bs + 8192 + wid * 1024;
  char* BsD3 = (char*)Bs + 12288 + wid * 1024;

  f32x4_t acc[2][4];
#pragma unroll
  for (int r = 0; r < 2; ++r)
#pragma unroll
    for (int c = 0; c < 4; ++c) acc[r][c] = (f32x4_t){0.f, 0.f, 0.f, 0.f};

  for (int k0 = 0; k0 < K; k0 += 64) {
    __syncthreads();
    gl16(Ag0 + k0, AsD0);
    gl16(Ag1 + k0, AsD1);
    gl16(Bg0 + k0, BsD0);
    gl16(Bg1 + k0, BsD1);
    gl16(Bg2 + k0, BsD2);
    gl16(Bg3 + k0, BsD3);
    __syncthreads();
    bfrag8 af[2][2], bfr[4][2];
#pragma unroll
    for (int rb = 0; rb < 2; ++rb)
#pragma unroll
      for (int h = 0; h < 2; ++h)
        af[rb][h] = *reinterpret_cast<const bfrag8*>(&As[(wm + rb * 16 + fr) * 64 + h * 32 + kb * 8]);
#pragma unroll
    for (int cb = 0; cb < 4; ++cb)
#pragma unroll
      for (int h = 0; h < 2; ++h)
        bfr[cb][h] = *reinterpret_cast<const bfrag8*>(&Bs[(wn + cb * 16 + fr) * 64 + h * 32 + kb * 8]);
#pragma unroll
    for (int rb = 0; rb < 2; ++rb)
#pragma unroll
      for (int cb = 0; cb < 4; ++cb) {
        acc[rb][cb] = __builtin_amdgcn_mfma_f32_16x16x32_bf16(af[rb][0], bfr[cb][0], acc[rb][cb], 0, 0, 0);
        acc[rb][cb] = __builtin_amdgcn_mfma_f32_16x16x32_bf16(af[rb][1], bfr[cb][1], acc[rb][cb], 0, 0, 0);
      }
  }

  // ---- fused epilogue ----
  const float SCL = 0.125f * 1.44269504f;
  int rowg = (lane >> 4) * 4, colg = lane & 15;
  int hsec = (n0 + wn) >> 6;   // wave-uniform head section, 0..23
  int odd = lane & 1;          // d parity (d = cb*16+colg)
  if (hsec < NH + NKV) {
    // Q or K: RoPE. Partner value (col d^1, same row) is in lane^1.
    unsigned short* dst = (hsec < NH) ? (Qh + (size_t)hsec * S_LEN * 64)
                                      : (Kh + (size_t)(hsec - NH) * S_LEN * 64);
    float scale = (hsec < NH) ? SCL : 1.0f;
#pragma unroll
    for (int rb = 0; rb < 2; ++rb)
#pragma unroll
      for (int cb = 0; cb < 4; ++cb) {
        int d = cb * 16 + colg;
        int i = d >> 1;
#pragma unroll
        for (int j = 0; j < 4; ++j) {
          int r = m0 + wm + rb * 16 + rowg + j;
          float v = acc[rb][cb][j];
          float p = __shfl_xor(v, 1);
          float co = pcos[r * 32 + i], si = psin[r * 32 + i];
          float o = odd ? (p * si + v * co) : (v * co - p * si);
          dst[(size_t)r * 64 + d] = f2bf(o * scale);
        }
      }
  } else {
    // V: transpose-scatter. 4 j-rows are consecutive -> one b64 write per (rb,cb).
    int hk = hsec - NH - NKV;
    unsigned short* dst = Vt + (size_t)hk * HDIM * S_LEN;
#pragma unroll
    for (int rb = 0; rb < 2; ++rb)
#pragma unroll
      for (int cb = 0; cb < 4; ++cb) {
        int d = cb * 16 + colg;
        int r0 = m0 + wm + rb * 16 + rowg;   // multiple of 4 -> 8B-aligned dest
        unsigned int u01 = (unsigned int)f2bf(acc[rb][cb][0]) | ((unsigned int)f2bf(acc[rb][cb][1]) << 16);
        unsigned int u23 = (unsigned int)f2bf(acc[rb][cb][2]) | ((unsigned int)f2bf(acc[rb][cb][3]) << 16);
        unsigned long long w = ((unsigned long long)u23 << 32) | u01;
        *reinterpret_cast<unsigned long long*>(&dst[(size_t)d * S_LEN + r0]) = w;
      }
  }
}

// ---------------- bf16 MFMA GEMM, 64x128 tile, BK=64: C = A * Bt^T (used for out-proj) ----------------
__global__ __launch_bounds__(256) void gemm_bf16(
    const unsigned short* __restrict__ A,
    const unsigned short* __restrict__ Bt,
    float* __restrict__ C, int M, int N, int K) {
  __shared__ __align__(16) unsigned short As[64 * 64];    // 8 KB
  __shared__ __align__(16) unsigned short Bs[128 * 64];   // 16 KB
  int m0 = blockIdx.x * 64, n0 = blockIdx.y * 128;
  int t = threadIdx.x, lane = t & 63, wid = t >> 6;
  int wm = (wid >> 1) * 32, wn = (wid & 1) * 64;
  int fr = lane & 15, kb = lane >> 4;
  int srow = t >> 3, scol = (t & 7) * 8;
  const unsigned short* Ag0 = A + (size_t)(m0 + srow) * K + scol;
  const unsigned short* Ag1 = A + (size_t)(m0 + 32 + srow) * K + scol;
  const unsigned short* Bg0 = Bt + (size_t)(n0 + srow) * K + scol;
  const unsigned short* Bg1 = Bt + (size_t)(n0 + 32 + srow) * K + scol;
  const unsigned short* Bg2 = Bt + (size_t)(n0 + 64 + srow) * K + scol;
  const unsigned short* Bg3 = Bt + (size_t)(n0 + 96 + srow) * K + scol;
  char* AsD0 = (char*)As + wid * 1024;
  char* AsD1 = (char*)As + 4096 + wid * 1024;
  char* BsD0 = (char*)Bs + wid * 1024;
  char* BsD1 = (char*)Bs + 4096 + wid * 1024;
  char* BsD2 = (char*)Bs + 8192 + wid * 1024;
  char* BsD3 = (char*)Bs + 12288 + wid * 1024;

  f32x4_t acc[2][4];
#pragma unroll
  for (int r = 0; r < 2; ++r)
#pragma unroll
    for (int c = 0; c < 4; ++c) acc[r][c] = (f32x4_t){0.f, 0.f, 0.f, 0.f};

  for (int k0 = 0; k0 < K; k0 += 64) {
    __syncthreads();
    gl16(Ag0 + k0, AsD0);
    gl16(Ag1 + k0, AsD1);
    gl16(Bg0 + k0, BsD0);
    gl16(Bg1 + k0, BsD1);
    gl16(Bg2 + k0, BsD2);
    gl16(Bg3 + k0, BsD3);
    __syncthreads();
    bfrag8 af[2][2], bfr[4][2];
#pragma unroll
    for (int rb = 0; rb < 2; ++rb)
#pragma unroll
      for (int h = 0; h < 2; ++h)
        af[rb][h] = *reinterpret_cast<const bfrag8*>(&As[(wm + rb * 16 + fr) * 64 + h * 32 + kb * 8]);
#pragma unroll
    for (int cb = 0; cb < 4; ++cb)
#pragma unroll
      for (int h = 0; h < 2; ++h)
        bfr[cb][h] = *reinterpret_cast<const bfrag8*>(&Bs[(wn + cb * 16 + fr) * 64 + h * 32 + kb * 8]);
#pragma unroll
    for (int rb = 0; rb < 2; ++rb)
#pragma unroll
      for (int cb = 0; cb < 4; ++cb) {
        acc[rb][cb] = __builtin_amdgcn_mfma_f32_16x16x32_bf16(af[rb][0], bfr[cb][0], acc[rb][cb], 0, 0, 0);
        acc[rb][cb] = __builtin_amdgcn_mfma_f32_16x16x32_bf16(af[rb][1], bfr[cb][1], acc[rb][cb], 0, 0, 0);
      }
  }
  int rowg = (lane >> 4) * 4, colg = lane & 15;
#pragma unroll
  for (int rb = 0; rb < 2; ++rb)
#pragma unroll
    for (int cb = 0; cb < 4; ++cb)
#pragma unroll
      for (int j = 0; j < 4; ++j) {
        int r = m0 + wm + rb * 16 + rowg + j;
        int c = n0 + wn + cb * 16 + colg;
        C[(size_t)r * N + c] = acc[rb][cb][j];
      }
}

// ---------------- flash attention (R13/R16-proven body + R19 XCD map): causal, GQA ----------------
// Qh [NH][S][64] (pre-scaled), Kh [NKV][S][64], Vt [NKV][64][S], aout [S][NH*64] bf16
// Block: 256 thr = 4 waves; all share one (head, 32-row q-tile), each takes 1/4 of KV range.
// Grid: 2048 blocks, longest-first. XCD-locality: hk = bid & 3 -> one kv-group per XCD (L2-resident).
// MERGE NOTE (R7 bug): m_r lives on lane fr (q-row g*16+fr); acc[g][dt][j] holds q-row g*16+rloc+j.
// Any factor derived from m MUST be broadcast via __shfl(x, rloc+j) before touching acc.
// l_r is LANE-PARTIAL (this lane's 16 columns); cross-kb reduced ONCE in the epilogue (R13).
__global__ __launch_bounds__(256) void flash_attn(
    const unsigned short* __restrict__ Qh,
    const unsigned short* __restrict__ Kh,
    const unsigned short* __restrict__ Vt,
    unsigned short* __restrict__ aout) {
  __shared__ __align__(16) char SMEM[18432];  // union: Pl[4][4KB] | 2 x merge region [36][64] f32
  int bid = blockIdx.x;
  int hk = bid & 3;                             // XCD-locality: one kv-group per XCD
  int head = hk * 4 + ((bid >> 2) & 3);
  int qt = 127 - (bid >> 4);                    // longest chains dispatch first
  int qrow0 = qt * 32;
  int t = threadIdx.x, lane = t & 63, wid = t >> 6;
  int fr = lane & 15, kb = lane >> 4, rloc = kb * 4;
  char* Pw = SMEM + wid * 4096;
  int swz = (fr & 7) << 4;  // XOR swizzle within 128B P rows

  const unsigned short* Qbase = Qh + ((size_t)head * S_LEN + qrow0) * 64;
  bfrag8 qf[2][2];
  qf[0][0] = *reinterpret_cast<const bfrag8*>(Qbase + fr * 64 + kb * 8);
  qf[0][1] = *reinterpret_cast<const bfrag8*>(Qbase + fr * 64 + 32 + kb * 8);
  qf[1][0] = *reinterpret_cast<const bfrag8*>(Qbase + (16 + fr) * 64 + kb * 8);
  qf[1][1] = *reinterpret_cast<const bfrag8*>(Qbase + (16 + fr) * 64 + 32 + kb * 8);

  const unsigned short* Kt = Kh + (size_t)hk * S_LEN * 64;
  const unsigned short* Vb = Vt + (size_t)hk * 64 * S_LEN;
  int koff = fr * 64 + kb * 8;
  int voff = fr * S_LEN + kb * 8;

  float m_r[2] = {-1e30f, -1e30f}, l_r[2] = {0.f, 0.f};
  f32x4_t acc[2][4];
#pragma unroll
  for (int g = 0; g < 2; ++g)
#pragma unroll
    for (int dt = 0; dt < 4; ++dt) acc[g][dt] = (f32x4_t){0.f, 0.f, 0.f, 0.f};

  int ntt = (qrow0 + 95) / 64;
  int nf = (qrow0 >= 63) ? ((qrow0 - 63) / 64 + 1) : 0;
  int c0 = (wid * ntt) >> 2, c1 = ((wid + 1) * ntt) >> 2;

  if (c0 < c1) {
    bfrag8 kf[4][2];
    {
      const unsigned short* K0 = Kt + c0 * 64 * 64 + koff;
#pragma unroll
      for (int ct = 0; ct < 4; ++ct) {
        kf[ct][0] = *reinterpret_cast<const bfrag8*>(K0 + ct * 1024);
        kf[ct][1] = *reinterpret_cast<const bfrag8*>(K0 + ct * 1024 + 32);
      }
    }
    for (int kt = c0; kt < c1; ++kt) {
      int kv0 = kt * 64;
      const unsigned short* Vtile = Vb + kv0 + voff;
      bfrag8 vf[2][4];
#pragma unroll
      for (int hh = 0; hh < 2; ++hh)
#pragma unroll
        for (int dt = 0; dt < 4; ++dt)
          vf[hh][dt] = *reinterpret_cast<const bfrag8*>(Vtile + dt * 16 * S_LEN + hh * 32);
      __builtin_amdgcn_sched_barrier(0);
      // swapped QK^T
      f32x4_t sc[2][4];
      __builtin_amdgcn_s_setprio(1);
#pragma unroll
      for (int ct = 0; ct < 4; ++ct) {
        f32x4_t z0 = (f32x4_t){0.f, 0.f, 0.f, 0.f};
        z0 = __builtin_amdgcn_mfma_f32_16x16x32_bf16(kf[ct][0], qf[0][0], z0, 0, 0, 0);
        sc[0][ct] = __builtin_amdgcn_mfma_f32_16x16x32_bf16(kf[ct][1], qf[0][1], z0, 0, 0, 0);
        f32x4_t z1 = (f32x4_t){0.f, 0.f, 0.f, 0.f};
        z1 = __builtin_amdgcn_mfma_f32_16x16x32_bf16(kf[ct][0], qf[1][0], z1, 0, 0, 0);
        sc[1][ct] = __builtin_amdgcn_mfma_f32_16x16x32_bf16(kf[ct][1], qf[1][1], z1, 0, 0, 0);
      }
      __builtin_amdgcn_s_setprio(0);
      // prefetch next tile's K
      if (kt + 1 < c1) {
        const unsigned short* Kn = Kt + (kv0 + 64) * 64 + koff;
#pragma unroll
        for (int ct = 0; ct < 4; ++ct) {
          kf[ct][0] = *reinterpret_cast<const bfrag8*>(Kn + ct * 1024);
          kf[ct][1] = *reinterpret_cast<const bfrag8*>(Kn + ct * 1024 + 32);
        }
      }
      __builtin_amdgcn_sched_barrier(0);
      if (kt >= nf) {
#pragma unroll
        for (int g = 0; g < 2; ++g) {
          int grow = qrow0 + g * 16 + fr;
#pragma unroll
          for (int ct = 0; ct < 4; ++ct)
#pragma unroll
            for (int j = 0; j < 4; ++j)
              sc[g][ct][j] = ((kv0 + ct * 16 + kb * 4 + j) <= grow) ? sc[g][ct][j] : -1e30f;
        }
      }
      // row max: v_max3 chains + 2 shuffles (m must be row-consistent before exp)
      float pmax[2];
#pragma unroll
      for (int g = 0; g < 2; ++g) {
        float pm = fmax3(sc[g][0][0], sc[g][0][1], sc[g][0][2]);
        pm = fmax3(pm, sc[g][0][3], sc[g][1][0]);
        pm = fmax3(pm, sc[g][1][1], sc[g][1][2]);
        pm = fmax3(pm, sc[g][1][3], sc[g][2][0]);
        pm = fmax3(pm, sc[g][2][1], sc[g][2][2]);
        pm = fmax3(pm, sc[g][2][3], sc[g][3][0]);
        pm = fmax3(pm, sc[g][3][1], sc[g][3][2]);
        pm = fmaxf(pm, sc[g][3][3]);
        pm = fmaxf(pm, __shfl_xor(pm, 16));
        pmax[g] = fmaxf(pm, __shfl_xor(pm, 32));
      }
      // defer-max (rescale factor a is row-uniform -> applies to lane-partial l too)
      bool need = (pmax[0] > m_r[0] + 8.0f) || (pmax[1] > m_r[1] + 8.0f);
      if (__any(need)) {
#pragma unroll
        for (int g = 0; g < 2; ++g) {
          float mnew = fmaxf(m_r[g], pmax[g]);
          float a = fexp2(m_r[g] - mnew);
          l_r[g] *= a;
          m_r[g] = mnew;
#pragma unroll
          for (int j = 0; j < 4; ++j) {
            float aj = __shfl(a, rloc + j);
#pragma unroll
            for (int dt = 0; dt < 4; ++dt) acc[g][dt][j] *= aj;
          }
        }
      }
      // P = exp2(s - m); TREE sum into LANE-PARTIAL l (no per-tile shuffles) [R13]
#pragma unroll
      for (int g = 0; g < 2; ++g) {
        float st[4];
#pragma unroll
        for (int ct = 0; ct < 4; ++ct) {
          float p0 = fexp2(sc[g][ct][0] - m_r[g]);
          float p1 = fexp2(sc[g][ct][1] - m_r[g]);
          float p2 = fexp2(sc[g][ct][2] - m_r[g]);
          float p3 = fexp2(sc[g][ct][3] - m_r[g]);
          sc[g][ct][0] = p0; sc[g][ct][1] = p1; sc[g][ct][2] = p2; sc[g][ct][3] = p3;
          st[ct] = (p0 + p1) + (p2 + p3);
        }
        l_r[g] += (st[0] + st[1]) + (st[2] + st[3]);
      }
      // P -> per-wave LDS
#pragma unroll
      for (int g = 0; g < 2; ++g)
#pragma unroll
        for (int ct = 0; ct < 4; ++ct) {
          unsigned int u01 = cvtpk_bf16(sc[g][ct][0], sc[g][ct][1]);
          unsigned int u23 = cvtpk_bf16(sc[g][ct][2], sc[g][ct][3]);
          unsigned long long w = ((unsigned long long)u23 << 32) | u01;
          *reinterpret_cast<unsigned long long*>(
              Pw + (g * 16 + fr) * 128 + ((ct * 32 + kb * 8) ^ swz)) = w;
        }
      // PV
      __builtin_amdgcn_s_setprio(1);
#pragma unroll
      for (int hh = 0; hh < 2; ++hh) {
        bfrag8 pa0 = *reinterpret_cast<const bfrag8*>(Pw + fr * 128 + ((hh * 64 + kb * 16) ^ swz));
        bfrag8 pa1 = *reinterpret_cast<const bfrag8*>(Pw + (16 + fr) * 128 + ((hh * 64 + kb * 16) ^ swz));
#pragma unroll
        for (int dt = 0; dt < 4; ++dt) {
          acc[0][dt] = __builtin_amdgcn_mfma_f32_16x16x32_bf16(pa0, vf[hh][dt], acc[0][dt], 0, 0, 0);
          acc[1][dt] = __builtin_amdgcn_mfma_f32_16x16x32_bf16(pa1, vf[hh][dt], acc[1][dt], 0, 0, 0);
        }
      }
      __builtin_amdgcn_s_setprio(0);
    }
  }

  // ---- log-tree merge: (0<-1, 2<-3) then (0<-2). Regions reuse P LDS. ----
  // l stays lane-partial through the merge (same layout in all waves; ca/cb row-uniform per lane).
  float* stgA = (float*)SMEM;
  float* stgB = (float*)(SMEM + 9216);
  __syncthreads();
  if (wid == 1 || wid == 3) {
    float* R = (wid == 1) ? stgA : stgB;
#pragma unroll
    for (int g = 0; g < 2; ++g) {
#pragma unroll
      for (int dt = 0; dt < 4; ++dt)
#pragma unroll
        for (int j = 0; j < 4; ++j)
          R[(g * 16 + dt * 4 + j) * 64 + lane] = acc[g][dt][j];
      R[(32 + g * 2) * 64 + lane] = m_r[g];
      R[(33 + g * 2) * 64 + lane] = l_r[g];
    }
  }
  __syncthreads();
  if (wid == 0 || wid == 2) {
    float* R = (wid == 0) ? stgA : stgB;
#pragma unroll
    for (int g = 0; g < 2; ++g) {
      float mo = R[(32 + g * 2) * 64 + lane], lo = R[(33 + g * 2) * 64 + lane];
      float mm = fmaxf(m_r[g], mo);
      float ca = fexp2(m_r[g] - mm), cb = fexp2(mo - mm);
      l_r[g] = l_r[g] * ca + lo * cb;
      m_r[g] = mm;
#pragma unroll
      for (int j = 0; j < 4; ++j) {
        float caj = __shfl(ca, rloc + j);   // row-matched factors (R7 fix)
        float cbj = __shfl(cb, rloc + j);
#pragma unroll
        for (int dt = 0; dt < 4; ++dt)
          acc[g][dt][j] = acc[g][dt][j] * caj + R[(g * 16 + dt * 4 + j) * 64 + lane] * cbj;
      }
    }
    if (wid == 2) {
#pragma unroll
      for (int g = 0; g < 2; ++g) {
#pragma unroll
        for (int dt = 0; dt < 4; ++dt)
#pragma unroll
          for (int j = 0; j < 4; ++j)
            stgB[(g * 16 + dt * 4 + j) * 64 + lane] = acc[g][dt][j];
        stgB[(32 + g * 2) * 64 + lane] = m_r[g];
        stgB[(33 + g * 2) * 64 + lane] = l_r[g];
      }
    }
  }
  __syncthreads();
  if (wid == 0) {
#pragma unroll
    for (int g = 0; g < 2; ++g) {
      float mo = stgB[(32 + g * 2) * 64 + lane], lo = stgB[(33 + g * 2) * 64 + lane];
      float mm = fmaxf(m_r[g], mo);
      float ca = fexp2(m_r[g] - mm), cb = fexp2(mo - mm);
      l_r[g] = l_r[g] * ca + lo * cb;
#pragma unroll
      for (int j = 0; j < 4; ++j) {
        float caj = __shfl(ca, rloc + j);   // row-matched factors (R7 fix)
        float cbj = __shfl(cb, rloc + j);
#pragma unroll
        for (int dt = 0; dt < 4; ++dt)
          acc[g][dt][j] = acc[g][dt][j] * caj + stgB[(g * 16 + dt * 4 + j) * 64 + lane] * cbj;
      }
    }
    // reduce lane-partial l across kb groups ONCE, then normalize and write
#pragma unroll
    for (int g = 0; g < 2; ++g) {
      l_r[g] += __shfl_xor(l_r[g], 16);
      l_r[g] += __shfl_xor(l_r[g], 32);
    }
#pragma unroll
    for (int g = 0; g < 2; ++g)
#pragma unroll
      for (int j = 0; j < 4; ++j) {
        float lj = __shfl(l_r[g], rloc + j);
        float inv = 1.0f / lj;
        int grow = qrow0 + g * 16 + rloc + j;
#pragma unroll
        for (int dt = 0; dt < 4; ++dt)
          aout[(size_t)grow * (NH * HDIM) + head * 64 + dt * 16 + fr] = f2bf(acc[g][dt][j] * inv);
      }
  }
}

// ---------------- launch ----------------
extern "C" void kernel_launch(void* const* d_in, const int* in_sizes, int n_in,
                              void* d_out, int out_size, void* d_ws, size_t ws_size,
                              hipStream_t stream) {
  const float* x    = (const float*)d_in[0];
  const float* pcos = (const float*)d_in[1];
  const float* psin = (const float*)d_in[2];
  const float* wqkv = (const float*)d_in[3];
  const float* wo   = (const float*)d_in[4];
  float* out = (float*)d_out;

  char* ws = (char*)d_ws;
  unsigned short* xb    = (unsigned short*)ws;  ws += (size_t)S_LEN * DMODEL * 2;
  unsigned short* wqkvT = (unsigned short*)ws;  ws += (size_t)NQKV * DMODEL * 2;
  unsigned short* woT   = (unsigned short*)ws;  ws += (size_t)DMODEL * DMODEL * 2;
  unsigned short* Qh    = (unsigned short*)ws;  ws += (size_t)NH * S_LEN * HDIM * 2;
  unsigned short* Kh    = (unsigned short*)ws;  ws += (size_t)NKV * S_LEN * HDIM * 2;
  unsigned short* Vt    = (unsigned short*)ws;  ws += (size_t)NKV * HDIM * S_LEN * 2;
  unsigned short* aoutb = (unsigned short*)ws;  ws += (size_t)S_LEN * NH * HDIM * 2;

  preprocess<<<dim3(4096 + 1536 + 1024), 256, 0, stream>>>(x, wqkv, wo, xb, wqkvT, woT);
  gemm_qkv_rope<<<dim3(S_LEN / 64, NQKV / 128), 256, 0, stream>>>(xb, wqkvT, pcos, psin, Qh, Kh, Vt);
  flash_attn<<<dim3(2048), 256, 0, stream>>>(Qh, Kh, Vt, aoutb);
  gemm_bf16<<<dim3(S_LEN / 64, DMODEL / 128), 256, 0, stream>>>(aoutb, woT, out, S_LEN, DMODEL, DMODEL);
}